// Round 1
// baseline (369.668 us; speedup 1.0000x reference)
//
#include <hip/hip_runtime.h>
#include <hip/hip_bf16.h>
#include <stdint.h>

typedef __attribute__((ext_vector_type(8))) short short8;
typedef __attribute__((ext_vector_type(8))) uint16_t ushort8;
typedef __attribute__((ext_vector_type(4))) float floatx4;

#define TK 64   // K elems staged per barrier pair (legacy kernel)

// ---------- helpers ----------

__device__ __forceinline__ uint16_t f2bf_bits(float f) {
    uint32_t u = __builtin_bit_cast(uint32_t, f);
    u += 0x7FFFu + ((u >> 16) & 1u);
    return (uint16_t)(u >> 16);
}

__device__ __forceinline__ void async_copy16(const void* g, void* l) {
    // global -> LDS direct copy, 16B/lane; LDS dest = wave-uniform base + lane*16
    auto gp = (const __attribute__((address_space(1))) uint32_t*)(uintptr_t)g;
    auto lp = (__attribute__((address_space(3))) uint32_t*)(uint32_t)(uintptr_t)l;
    __builtin_amdgcn_global_load_lds(gp, lp, 16, 0, 0);
}

// ---------- fp32 -> bf16 conversion kernels ----------

__global__ void cvt8(const float* __restrict__ src, uint16_t* __restrict__ dst, int n) {
    int i = (blockIdx.x * 256 + threadIdx.x) * 8;
    if (i >= n) return;
    floatx4 a = *(const floatx4*)(src + i);
    floatx4 b = *(const floatx4*)(src + i + 4);
    ushort8 o;
#pragma unroll
    for (int k = 0; k < 4; k++) {
        o[k]     = f2bf_bits(a[k]);
        o[k + 4] = f2bf_bits(b[k]);
    }
    *(ushort8*)(dst + i) = o;
}

// W2 [51][2048] fp32 -> [64][2048] bf16, rows >= 51 zeroed
__global__ void cvt_pad_w2(const float* __restrict__ src, uint16_t* __restrict__ dst) {
    int i = (blockIdx.x * 256 + threadIdx.x) * 8;   // over 64*2048
    int row = i >> 11;
    ushort8 o;
    if (row < 51) {
        floatx4 a = *(const floatx4*)(src + i);
        floatx4 b = *(const floatx4*)(src + i + 4);
#pragma unroll
        for (int k = 0; k < 4; k++) {
            o[k]     = f2bf_bits(a[k]);
            o[k + 4] = f2bf_bits(b[k]);
        }
    } else {
#pragma unroll
        for (int k = 0; k < 8; k++) o[k] = 0;
    }
    *(ushort8*)(dst + i) = o;
}

// ---------- legacy small-tile GEMM (kept for layer 2: N=64) ----------
// C[m,n] = act( sum_k A[m,k]*W[n,k] + bias[n] )

template <int MI, int NJ, bool RELU, bool OUTF32>
__global__ __launch_bounds__(256, 2)
void gemm_bt(const uint16_t* __restrict__ A,
             const uint16_t* __restrict__ W,
             const float* __restrict__ bias,
             void* __restrict__ out,
             int M, int N, int K, int ldc, int nstore)
{
    constexpr int TMv = MI * 32;
    constexpr int TNv = NJ * 32;
    constexpr int ACH = TMv / 32;
    constexpr int BCH = TNv / 32;

    __shared__ alignas(16) uint16_t sA[TMv * TK];
    __shared__ alignas(16) uint16_t sB[TNv * TK];

    const int tid  = threadIdx.x;
    const int wave = tid >> 6;
    const int lane = tid & 63;

    const int f   = blockIdx.x;
    const int xcd = f & 7;
    const int loc = f >> 3;
    const int per = (int)gridDim.x >> 3;
    const int nt  = N / TNv;
    const int n_t = loc % nt;
    const int m_t = xcd * (per / nt) + loc / nt;
    const int n0 = n_t * TNv;
    const int m0 = m_t * TMv;

    floatx4 acc[MI][NJ];
    const floatx4 zero = {0.f, 0.f, 0.f, 0.f};
#pragma unroll
    for (int i = 0; i < MI; i++)
#pragma unroll
        for (int j = 0; j < NJ; j++) acc[i][j] = zero;

    const int wr = (wave >> 1) * MI * 16;
    const int wc = (wave & 1) * NJ * 16;

    const int sr   = lane >> 3;
    const int scol = ((lane & 7) ^ sr) * 8;

    const uint16_t* ap[ACH];
    const uint16_t* bp[BCH];
#pragma unroll
    for (int t = 0; t < ACH; t++)
        ap[t] = A + (size_t)(m0 + (wave + 4 * t) * 8 + sr) * K + scol;
#pragma unroll
    for (int t = 0; t < BCH; t++)
        bp[t] = W + (size_t)(n0 + (wave + 4 * t) * 8 + sr) * K + scol;

    const int fm = lane & 15;
    const int fr = fm & 7;
    const int kgb = lane >> 4;

    const int niter = K / TK;
    for (int it = 0; it < niter; it++) {
#pragma unroll
        for (int t = 0; t < ACH; t++) {
            async_copy16(ap[t], sA + (wave + 4 * t) * 512);
            ap[t] += TK;
        }
#pragma unroll
        for (int t = 0; t < BCH; t++) {
            async_copy16(bp[t], sB + (wave + 4 * t) * 512);
            bp[t] += TK;
        }
        __syncthreads();

#pragma unroll
        for (int kk = 0; kk < 2; kk++) {
            const int slot = ((kgb + 4 * kk) ^ fr) * 8;
            short8 af[MI], bfr[NJ];
#pragma unroll
            for (int i = 0; i < MI; i++)
                af[i] = *(const short8*)(sA + (wr + i * 16 + fm) * TK + slot);
#pragma unroll
            for (int j = 0; j < NJ; j++)
                bfr[j] = *(const short8*)(sB + (wc + j * 16 + fm) * TK + slot);
#pragma unroll
            for (int i = 0; i < MI; i++)
#pragma unroll
                for (int j = 0; j < NJ; j++)
                    acc[i][j] = __builtin_amdgcn_mfma_f32_16x16x32_bf16(af[i], bfr[j], acc[i][j], 0, 0, 0);
        }
        __syncthreads();
    }

    const int cr = (lane >> 4) * 4;
    const int cc = lane & 15;
#pragma unroll
    for (int i = 0; i < MI; i++) {
        const int gmb = m0 + wr + i * 16 + cr;
#pragma unroll
        for (int j = 0; j < NJ; j++) {
            const int gn = n0 + wc + j * 16 + cc;
            if (gn < nstore) {
                const float bv = bias[gn];
#pragma unroll
                for (int r = 0; r < 4; r++) {
                    float v = acc[i][j][r] + bv;
                    if (RELU) v = fmaxf(v, 0.f);
                    const size_t idx = (size_t)(gmb + r) * ldc + gn;
                    if (OUTF32) ((float*)out)[idx] = v;
                    else        ((uint16_t*)out)[idx] = f2bf_bits(v);
                }
            }
        }
    }
}

// ---------- 256x256 8-phase GEMM (T2+T3+T4+T5) for layers 0/1 ----------
// 8 waves (2M x 4N), 512 threads, BK=64, LDS 128 KiB (2 bufs x (A 256x64 + B 256x64)).
// Per phase: 12 ds_read_b128 (one block C-quadrant's frags) + 1 half-tile
// global_load_lds prefetch; counted vmcnt(4) only at phases 4 and 8.
// Quadrant order Q00,Q01,Q11,Q10 releases A0 after P2, B1 after P3, A1/B0 after P4,
// which makes the stage schedule below hazard-free (derivation in session notes).

#define PH_PRE(QM, QN, SA, SB) \
    short8 af[4][2], bf[2][2]; \
    { const uint16_t* sAq = (SA) + (QM) * 8192 + aoff; \
      const uint16_t* sBq = (SB) + (QN) * 8192 + boff; \
      _Pragma("unroll") \
      for (int kk = 0; kk < 2; kk++) { \
        const int sl = ((kgb + 4 * kk) ^ fr) * 8; \
        _Pragma("unroll") \
        for (int mi = 0; mi < 4; mi++) af[mi][kk] = *(const short8*)(sAq + mi * 1024 + sl); \
        _Pragma("unroll") \
        for (int nj = 0; nj < 2; nj++) bf[nj][kk] = *(const short8*)(sBq + nj * 1024 + sl); \
      } }

#define PH_POST(QM, QN) \
    __builtin_amdgcn_sched_barrier(0); \
    __builtin_amdgcn_s_barrier(); \
    asm volatile("s_waitcnt lgkmcnt(0)" ::: "memory"); \
    __builtin_amdgcn_sched_barrier(0); \
    __builtin_amdgcn_s_setprio(1); \
    _Pragma("unroll") \
    for (int kk = 0; kk < 2; kk++) \
      _Pragma("unroll") \
      for (int mi = 0; mi < 4; mi++) \
        _Pragma("unroll") \
        for (int nj = 0; nj < 2; nj++) \
          acc[QM][QN][mi][nj] = __builtin_amdgcn_mfma_f32_16x16x32_bf16( \
              af[mi][kk], bf[nj][kk], acc[QM][QN][mi][nj], 0, 0, 0); \
    __builtin_amdgcn_s_setprio(0); \
    __builtin_amdgcn_sched_barrier(0); \
    __builtin_amdgcn_s_barrier(); \
    __builtin_amdgcn_sched_barrier(0);

template <bool RELU, bool OUTF32>
__global__ __launch_bounds__(512, 2)
void gemm256(const uint16_t* __restrict__ A,
             const uint16_t* __restrict__ W,
             const float* __restrict__ bias,
             void* __restrict__ out,
             int K, int N, int ldc, int nstore)
{
    extern __shared__ uint16_t smem[];   // 65536 uint16 = 128 KiB
    uint16_t* sA0 = smem;                // A buf0 (even K-tiles)
    uint16_t* sA1 = smem + 16384;        // A buf1 (odd K-tiles)
    uint16_t* sB0 = smem + 32768;
    uint16_t* sB1 = smem + 49152;

    const int tid  = threadIdx.x;
    const int wave = tid >> 6;          // 0..7
    const int lane = tid & 63;
    const int wm2  = wave >> 2;         // 0..1
    const int wn2  = wave & 3;          // 0..3

    // XCD-aware tile assignment (grid % 8 == 0, per % ntn == 0)
    const int f   = blockIdx.x;
    const int xcd = f & 7;
    const int loc = f >> 3;
    const int per = (int)gridDim.x >> 3;
    const int ntn = N / 256;
    const int n_t = loc % ntn;
    const int m_t = xcd * (per / ntn) + loc / ntn;
    const int m0 = m_t * 256;
    const int n0 = n_t * 256;

    floatx4 acc[2][2][4][2];
    const floatx4 zero = {0.f, 0.f, 0.f, 0.f};
#pragma unroll
    for (int qm = 0; qm < 2; qm++)
#pragma unroll
    for (int qn = 0; qn < 2; qn++)
#pragma unroll
    for (int mi = 0; mi < 4; mi++)
#pragma unroll
    for (int nj = 0; nj < 2; nj++) acc[qm][qn][mi][nj] = zero;

    // staging addressing: 1KB chunk = 8 rows x 64 cols; slot s of row r holds
    // global k-group s ^ (r&7)  (bank-conflict-free frag reads; proven 0-conflict)
    const int srow = lane >> 3;
    const int scol = ((lane & 7) ^ srow) * 8;
    const uint16_t* pA = A + (size_t)(m0 + wave * 8 + srow) * K + scol;
    const uint16_t* pB = W + (size_t)(n0 + wave * 8 + srow) * K + scol;

    auto stA = [&](int h, int kt, uint16_t* buf) {
        const uint16_t* p = pA + (size_t)h * 128 * K + (size_t)kt * 64;
        async_copy16(p,                 buf + h * 8192 + wave * 512);
        async_copy16(p + (size_t)64 * K, buf + h * 8192 + 4096 + wave * 512);
    };
    auto stB = [&](int h, int kt, uint16_t* buf) {
        const uint16_t* p = pB + (size_t)h * 128 * K + (size_t)kt * 64;
        async_copy16(p,                 buf + h * 8192 + wave * 512);
        async_copy16(p + (size_t)64 * K, buf + h * 8192 + 4096 + wave * 512);
    };

    // fragment addressing
    const int fm  = lane & 15;
    const int fr  = fm & 7;
    const int kgb = lane >> 4;                 // 0..3
    const int aoff = (wm2 * 64 + fm) * 64;
    const int boff = (wn2 * 32 + fm) * 64;

    // ---- prologue: tile0 complete + {A0,B1}(tile1) in flight ----
    stA(0, 0, sA0);
    stB(0, 0, sB0);
    stA(1, 0, sA0);
    stB(1, 0, sB0);
    stA(0, 1, sA1);
    stB(1, 1, sB1);
    asm volatile("s_waitcnt vmcnt(4)" ::: "memory");   // tile0 landed; 2 half-tiles in flight
    __builtin_amdgcn_s_barrier();
    __builtin_amdgcn_sched_barrier(0);

    const int niter2 = K / 128;    // 2 K-tiles per iteration
    for (int it = 0; it < niter2; ++it) {
        const int T = 2 * it;
        const bool last = (it == niter2 - 1);

        // P1: Q00 of tile T (buf0); stage B0(T+1) -> buf1
        { PH_PRE(0, 0, sA0, sB0);
          stB(0, T + 1, sB1);
          asm volatile("s_waitcnt lgkmcnt(8)");
          PH_POST(0, 0); }

        // P2: Q01; stage A1(T+1) -> buf1
        { PH_PRE(0, 1, sA0, sB0);
          stA(1, T + 1, sA1);
          asm volatile("s_waitcnt lgkmcnt(8)");
          PH_POST(0, 1); }

        // P3: Q11; stage A0(T+2) -> buf0 (A0 released after P2)
        { PH_PRE(1, 1, sA0, sB0);
          if (!last) stA(0, T + 2, sA0);
          asm volatile("s_waitcnt lgkmcnt(8)");
          PH_POST(1, 1); }

        // P4: Q10; stage B1(T+2) -> buf0 (B1 released after P3); vmcnt checkpoint
        { PH_PRE(1, 0, sA0, sB0);
          if (!last) stB(1, T + 2, sB0);
          asm volatile("s_waitcnt lgkmcnt(8)");
          if (last) asm volatile("s_waitcnt vmcnt(0)" ::: "memory");
          else      asm volatile("s_waitcnt vmcnt(4)" ::: "memory");  // tile T+1 landed
          PH_POST(1, 0); }

        // P5: Q00 of tile T+1 (buf1); stage B0(T+2) -> buf0
        { PH_PRE(0, 0, sA1, sB1);
          if (!last) stB(0, T + 2, sB0);
          asm volatile("s_waitcnt lgkmcnt(8)");
          PH_POST(0, 0); }

        // P6: Q01; stage A1(T+2) -> buf0
        { PH_PRE(0, 1, sA1, sB1);
          if (!last) stA(1, T + 2, sA0);
          asm volatile("s_waitcnt lgkmcnt(8)");
          PH_POST(0, 1); }

        // P7: Q11; stage A0(T+3) -> buf1
        { PH_PRE(1, 1, sA1, sB1);
          if (!last) stA(0, T + 3, sA1);
          asm volatile("s_waitcnt lgkmcnt(8)");
          PH_POST(1, 1); }

        // P8: Q10; stage B1(T+3) -> buf1; vmcnt checkpoint
        { PH_PRE(1, 0, sA1, sB1);
          if (!last) {
            stB(1, T + 3, sB1);
            asm volatile("s_waitcnt lgkmcnt(8)");
            asm volatile("s_waitcnt vmcnt(4)" ::: "memory");  // tile T+2 landed
          }
          PH_POST(1, 0); }
    }

    // ---- epilogue: C/D layout col = lane&15, row = (lane>>4)*4 + reg ----
    const int cr = (lane >> 4) * 4;
    const int cc = lane & 15;
#pragma unroll
    for (int qm = 0; qm < 2; qm++)
#pragma unroll
    for (int mi = 0; mi < 4; mi++) {
        const int gm = m0 + qm * 128 + wm2 * 64 + mi * 16 + cr;
#pragma unroll
        for (int qn = 0; qn < 2; qn++)
#pragma unroll
        for (int nj = 0; nj < 2; nj++) {
            const int gn = n0 + qn * 128 + wn2 * 32 + nj * 16 + cc;
            if (gn < nstore) {
                const float bv = bias[gn];
#pragma unroll
                for (int r = 0; r < 4; r++) {
                    float v = acc[qm][qn][mi][nj][r] + bv;
                    if (RELU) v = fmaxf(v, 0.f);
                    const size_t idx = (size_t)(gm + r) * ldc + gn;
                    if (OUTF32) ((float*)out)[idx] = v;
                    else        ((uint16_t*)out)[idx] = f2bf_bits(v);
                }
            }
        }
    }
}

// ---------- launch ----------

extern "C" void kernel_launch(void* const* d_in, const int* in_sizes, int n_in,
                              void* d_out, int out_size, void* d_ws, size_t ws_size,
                              hipStream_t stream) {
    (void)in_sizes; (void)n_in; (void)out_size; (void)ws_size;
    const float* X  = (const float*)d_in[1];
    const float* W0 = (const float*)d_in[3];
    const float* b0 = (const float*)d_in[4];
    const float* W1 = (const float*)d_in[5];
    const float* b1 = (const float*)d_in[6];
    const float* W2 = (const float*)d_in[7];
    const float* b2 = (const float*)d_in[8];

    const int M = 16384;     // 16 batches * 1024 pairs

    static bool attr_done = false;
    if (!attr_done) {
        (void)hipFuncSetAttribute((const void*)gemm256<true, false>,
                                  hipFuncAttributeMaxDynamicSharedMemorySize, 131072);
        attr_done = true;
    }

    char* w = (char*)d_ws;
    uint16_t* X0  = (uint16_t*)w; w += (size_t)M * 1024 * 2;
    uint16_t* X1  = (uint16_t*)w; w += (size_t)M * 2048 * 2;
    uint16_t* X2  = (uint16_t*)w; w += (size_t)M * 2048 * 2;
    uint16_t* W0b = (uint16_t*)w; w += (size_t)2048 * 1024 * 2;
    uint16_t* W1b = (uint16_t*)w; w += (size_t)2048 * 2048 * 2;
    uint16_t* W2b = (uint16_t*)w; w += (size_t)64 * 2048 * 2;

    cvt8<<<M * 1024 / 8 / 256, 256, 0, stream>>>(X, X0, M * 1024);
    cvt8<<<2048 * 1024 / 8 / 256, 256, 0, stream>>>(W0, W0b, 2048 * 1024);
    cvt8<<<2048 * 2048 / 8 / 256, 256, 0, stream>>>(W1, W1b, 2048 * 2048);
    cvt_pad_w2<<<64 * 2048 / 8 / 256, 256, 0, stream>>>(W2, W2b);

    // layer 0: [16384,1024] x [2048,1024]^T -> relu -> bf16; 256x256 8-phase
    gemm256<true, false><<<dim3((M / 256) * (2048 / 256)), 512, 131072, stream>>>(
        X0, W0b, b0, X1, 1024, 2048, 2048, 2048);
    // layer 1: [16384,2048] x [2048,2048]^T -> relu -> bf16; 256x256 8-phase
    gemm256<true, false><<<dim3((M / 256) * (2048 / 256)), 512, 131072, stream>>>(
        X1, W1b, b1, X2, 2048, 2048, 2048, 2048);
    // layer 2: [16384,2048] x [64(pad 51),2048]^T -> fp32; 32x64 tiles, 512 blocks
    gemm_bt<1, 2, false, true><<<dim3(M / 32), 256, 0, stream>>>(
        X2, W2b, b2, d_out, M, 64, 2048, 51, 51);
}

// Round 2
// 349.059 us; speedup vs baseline: 1.0590x; 1.0590x over previous
//
#include <hip/hip_runtime.h>
#include <hip/hip_bf16.h>
#include <stdint.h>

typedef __attribute__((ext_vector_type(8))) short short8;
typedef __attribute__((ext_vector_type(8))) uint16_t ushort8;
typedef __attribute__((ext_vector_type(4))) float floatx4;

#define TK 64   // K elems staged per barrier pair (legacy kernel)

// ---------- helpers ----------

__device__ __forceinline__ uint16_t f2bf_bits(float f) {
    uint32_t u = __builtin_bit_cast(uint32_t, f);
    u += 0x7FFFu + ((u >> 16) & 1u);
    return (uint16_t)(u >> 16);
}

__device__ __forceinline__ void async_copy16(const void* g, void* l) {
    // global -> LDS direct copy, 16B/lane; LDS dest = wave-uniform base + lane*16
    auto gp = (const __attribute__((address_space(1))) uint32_t*)(uintptr_t)g;
    auto lp = (__attribute__((address_space(3))) uint32_t*)(uint32_t)(uintptr_t)l;
    __builtin_amdgcn_global_load_lds(gp, lp, 16, 0, 0);
}

// ---------- fp32 -> bf16 conversion kernels ----------

__global__ void cvt8(const float* __restrict__ src, uint16_t* __restrict__ dst, int n) {
    int i = (blockIdx.x * 256 + threadIdx.x) * 8;
    if (i >= n) return;
    floatx4 a = *(const floatx4*)(src + i);
    floatx4 b = *(const floatx4*)(src + i + 4);
    ushort8 o;
#pragma unroll
    for (int k = 0; k < 4; k++) {
        o[k]     = f2bf_bits(a[k]);
        o[k + 4] = f2bf_bits(b[k]);
    }
    *(ushort8*)(dst + i) = o;
}

// W2 [51][2048] fp32 -> [64][2048] bf16, rows >= 51 zeroed
__global__ void cvt_pad_w2(const float* __restrict__ src, uint16_t* __restrict__ dst) {
    int i = (blockIdx.x * 256 + threadIdx.x) * 8;   // over 64*2048
    int row = i >> 11;
    ushort8 o;
    if (row < 51) {
        floatx4 a = *(const floatx4*)(src + i);
        floatx4 b = *(const floatx4*)(src + i + 4);
#pragma unroll
        for (int k = 0; k < 4; k++) {
            o[k]     = f2bf_bits(a[k]);
            o[k + 4] = f2bf_bits(b[k]);
        }
    } else {
#pragma unroll
        for (int k = 0; k < 8; k++) o[k] = 0;
    }
    *(ushort8*)(dst + i) = o;
}

// ---------- legacy small-tile GEMM (kept for layer 2: N=64) ----------
// C[m,n] = act( sum_k A[m,k]*W[n,k] + bias[n] )

template <int MI, int NJ, bool RELU, bool OUTF32>
__global__ __launch_bounds__(256, 2)
void gemm_bt(const uint16_t* __restrict__ A,
             const uint16_t* __restrict__ W,
             const float* __restrict__ bias,
             void* __restrict__ out,
             int M, int N, int K, int ldc, int nstore)
{
    constexpr int TMv = MI * 32;
    constexpr int TNv = NJ * 32;
    constexpr int ACH = TMv / 32;
    constexpr int BCH = TNv / 32;

    __shared__ alignas(16) uint16_t sA[TMv * TK];
    __shared__ alignas(16) uint16_t sB[TNv * TK];

    const int tid  = threadIdx.x;
    const int wave = tid >> 6;
    const int lane = tid & 63;

    const int f   = blockIdx.x;
    const int xcd = f & 7;
    const int loc = f >> 3;
    const int per = (int)gridDim.x >> 3;
    const int nt  = N / TNv;
    const int n_t = loc % nt;
    const int m_t = xcd * (per / nt) + loc / nt;
    const int n0 = n_t * TNv;
    const int m0 = m_t * TMv;

    floatx4 acc[MI][NJ];
    const floatx4 zero = {0.f, 0.f, 0.f, 0.f};
#pragma unroll
    for (int i = 0; i < MI; i++)
#pragma unroll
        for (int j = 0; j < NJ; j++) acc[i][j] = zero;

    const int wr = (wave >> 1) * MI * 16;
    const int wc = (wave & 1) * NJ * 16;

    const int sr   = lane >> 3;
    const int scol = ((lane & 7) ^ sr) * 8;

    const uint16_t* ap[ACH];
    const uint16_t* bp[BCH];
#pragma unroll
    for (int t = 0; t < ACH; t++)
        ap[t] = A + (size_t)(m0 + (wave + 4 * t) * 8 + sr) * K + scol;
#pragma unroll
    for (int t = 0; t < BCH; t++)
        bp[t] = W + (size_t)(n0 + (wave + 4 * t) * 8 + sr) * K + scol;

    const int fm = lane & 15;
    const int fr = fm & 7;
    const int kgb = lane >> 4;

    const int niter = K / TK;
    for (int it = 0; it < niter; it++) {
#pragma unroll
        for (int t = 0; t < ACH; t++) {
            async_copy16(ap[t], sA + (wave + 4 * t) * 512);
            ap[t] += TK;
        }
#pragma unroll
        for (int t = 0; t < BCH; t++) {
            async_copy16(bp[t], sB + (wave + 4 * t) * 512);
            bp[t] += TK;
        }
        __syncthreads();

#pragma unroll
        for (int kk = 0; kk < 2; kk++) {
            const int slot = ((kgb + 4 * kk) ^ fr) * 8;
            short8 af[MI], bfr[NJ];
#pragma unroll
            for (int i = 0; i < MI; i++)
                af[i] = *(const short8*)(sA + (wr + i * 16 + fm) * TK + slot);
#pragma unroll
            for (int j = 0; j < NJ; j++)
                bfr[j] = *(const short8*)(sB + (wc + j * 16 + fm) * TK + slot);
#pragma unroll
            for (int i = 0; i < MI; i++)
#pragma unroll
                for (int j = 0; j < NJ; j++)
                    acc[i][j] = __builtin_amdgcn_mfma_f32_16x16x32_bf16(af[i], bfr[j], acc[i][j], 0, 0, 0);
        }
        __syncthreads();
    }

    const int cr = (lane >> 4) * 4;
    const int cc = lane & 15;
#pragma unroll
    for (int i = 0; i < MI; i++) {
        const int gmb = m0 + wr + i * 16 + cr;
#pragma unroll
        for (int j = 0; j < NJ; j++) {
            const int gn = n0 + wc + j * 16 + cc;
            if (gn < nstore) {
                const float bv = bias[gn];
#pragma unroll
                for (int r = 0; r < 4; r++) {
                    float v = acc[i][j][r] + bv;
                    if (RELU) v = fmaxf(v, 0.f);
                    const size_t idx = (size_t)(gmb + r) * ldc + gn;
                    if (OUTF32) ((float*)out)[idx] = v;
                    else        ((uint16_t*)out)[idx] = f2bf_bits(v);
                }
            }
        }
    }
}

// ---------- 256x256 8-phase GEMM with register-carried fragments ----------
// 8 waves (2M x 4N), 512 threads, BK=64, LDS 128 KiB (2 bufs x (A 256x64 + B 256x64)).
// Quadrant walk Q00->Q01->Q11->Q10 with fragment reuse:
//   P1: load A0(af)+B0(b0) [12 rd]  P2: load B1(b1) [4 rd]
//   P3: load A1(af)        [8 rd]   P4: none (reuse af,b0) [0 rd]
// -> 24 ds_read_b128 per K-tile = minimum (each fragment read once).
// Staging: one half-tile per phase; vmcnt(6) checkpoints at P4/P8 only
// (3 half-tiles in flight). Buffer regions are staged only in phases AFTER
// their last ds_read completed (separated by barrier + lgkmcnt(0)).

#define SCHED0 __builtin_amdgcn_sched_barrier(0)

#define LOAD_A(SA, QM) do { \
    const uint16_t* _p = (SA) + (QM) * 8192 + aoff; \
    _Pragma("unroll") \
    for (int kk = 0; kk < 2; kk++) { \
      const int sl = ((kgb + 4 * kk) ^ fr) * 8; \
      _Pragma("unroll") \
      for (int mi = 0; mi < 4; mi++) \
        af[mi][kk] = *(const short8*)(_p + mi * 1024 + sl); \
    } } while (0)

#define LOAD_B(SB, QN, BF) do { \
    const uint16_t* _p = (SB) + (QN) * 8192 + boff; \
    _Pragma("unroll") \
    for (int kk = 0; kk < 2; kk++) { \
      const int sl = ((kgb + 4 * kk) ^ fr) * 8; \
      _Pragma("unroll") \
      for (int nj = 0; nj < 2; nj++) \
        BF[nj][kk] = *(const short8*)(_p + nj * 1024 + sl); \
    } } while (0)

#define PH_MFMA(QM, QN, BF) \
    SCHED0; \
    __builtin_amdgcn_s_barrier(); \
    asm volatile("s_waitcnt lgkmcnt(0)" ::: "memory"); \
    SCHED0; \
    __builtin_amdgcn_s_setprio(1); \
    _Pragma("unroll") \
    for (int kk = 0; kk < 2; kk++) \
      _Pragma("unroll") \
      for (int mi = 0; mi < 4; mi++) \
        _Pragma("unroll") \
        for (int nj = 0; nj < 2; nj++) \
          acc[QM][QN][mi][nj] = __builtin_amdgcn_mfma_f32_16x16x32_bf16( \
              af[mi][kk], BF[nj][kk], acc[QM][QN][mi][nj], 0, 0, 0); \
    __builtin_amdgcn_s_setprio(0); \
    SCHED0; \
    __builtin_amdgcn_s_barrier(); \
    SCHED0;

// One iteration = 2 K-tiles (T in buf0, T+1 in buf1), 8 phases.
#define ITER_BODY(T, LAST) \
    /* P1: Q00(T); stage A1(T+1)->buf1 */ \
    LOAD_A(sA0, 0); \
    LOAD_B(sB0, 0, b0); \
    stA(1, (T) + 1, sA1); \
    asm volatile("s_waitcnt lgkmcnt(8)"); \
    PH_MFMA(0, 0, b0); \
    /* P2: Q01(T); stage A0(T+2)->buf0 (A0 reads done P1) */ \
    LOAD_B(sB0, 1, b1); \
    if (!(LAST)) stA(0, (T) + 2, sA0); \
    PH_MFMA(0, 1, b1); \
    /* P3: Q11(T); stage B0(T+2)->buf0 (B0 reads done P1) */ \
    LOAD_A(sA0, 1); \
    if (!(LAST)) stB(0, (T) + 2, sB0); \
    PH_MFMA(1, 1, b1); \
    /* P4: Q10(T) pure MFMA (af=A1 from P3, b0 from P1); stage B1(T+2); ckpt */ \
    if (!(LAST)) { \
      stB(1, (T) + 2, sB0); \
      asm volatile("s_waitcnt vmcnt(6)" ::: "memory"); \
    } else { \
      asm volatile("s_waitcnt vmcnt(0)" ::: "memory"); \
    } \
    PH_MFMA(1, 0, b0); \
    /* P5: Q00(T+1); stage A1(T+2)->buf0 (A1 reads done P3) */ \
    LOAD_A(sA1, 0); \
    LOAD_B(sB1, 0, b0); \
    if (!(LAST)) stA(1, (T) + 2, sA0); \
    asm volatile("s_waitcnt lgkmcnt(8)"); \
    PH_MFMA(0, 0, b0); \
    /* P6: Q01(T+1); stage A0(T+3)->buf1 */ \
    LOAD_B(sB1, 1, b1); \
    if (!(LAST)) stA(0, (T) + 3, sA1); \
    PH_MFMA(0, 1, b1); \
    /* P7: Q11(T+1); stage B0(T+3)->buf1 */ \
    LOAD_A(sA1, 1); \
    if (!(LAST)) stB(0, (T) + 3, sB1); \
    PH_MFMA(1, 1, b1); \
    /* P8: Q10(T+1) pure MFMA; stage B1(T+3)->buf1; ckpt */ \
    if (!(LAST)) { \
      stB(1, (T) + 3, sB1); \
      asm volatile("s_waitcnt vmcnt(6)" ::: "memory"); \
    } \
    PH_MFMA(1, 0, b0);

template <bool RELU, bool OUTF32>
__global__ __launch_bounds__(512, 2)
void gemm256(const uint16_t* __restrict__ A,
             const uint16_t* __restrict__ W,
             const float* __restrict__ bias,
             void* __restrict__ out,
             int K, int N, int ldc, int nstore)
{
    extern __shared__ uint16_t smem[];   // 65536 uint16 = 128 KiB
    uint16_t* sA0 = smem;                // A buf0 (even K-tiles)
    uint16_t* sA1 = smem + 16384;        // A buf1 (odd K-tiles)
    uint16_t* sB0 = smem + 32768;
    uint16_t* sB1 = smem + 49152;

    const int tid  = threadIdx.x;
    const int wave = tid >> 6;          // 0..7
    const int lane = tid & 63;
    const int wm2  = wave >> 2;         // 0..1
    const int wn2  = wave & 3;          // 0..3

    // XCD-aware tile assignment (grid % 8 == 0, per % ntn == 0)
    const int f   = blockIdx.x;
    const int xcd = f & 7;
    const int loc = f >> 3;
    const int per = (int)gridDim.x >> 3;
    const int ntn = N / 256;
    const int n_t = loc % ntn;
    const int m_t = xcd * (per / ntn) + loc / ntn;
    const int m0 = m_t * 256;
    const int n0 = n_t * 256;

    floatx4 acc[2][2][4][2];
    const floatx4 zero = {0.f, 0.f, 0.f, 0.f};
#pragma unroll
    for (int qm = 0; qm < 2; qm++)
#pragma unroll
    for (int qn = 0; qn < 2; qn++)
#pragma unroll
    for (int mi = 0; mi < 4; mi++)
#pragma unroll
    for (int nj = 0; nj < 2; nj++) acc[qm][qn][mi][nj] = zero;

    // staging addressing: 1KB chunk = 8 rows x 64 cols; slot s of row r holds
    // global k-group s ^ (r&7)  (bank-conflict-free frag reads; proven 0-conflict)
    const int srow = lane >> 3;
    const int scol = ((lane & 7) ^ srow) * 8;
    const uint16_t* pA = A + (size_t)(m0 + wave * 8 + srow) * K + scol;
    const uint16_t* pB = W + (size_t)(n0 + wave * 8 + srow) * K + scol;

    auto stA = [&](int h, int kt, uint16_t* buf) {
        const uint16_t* p = pA + (size_t)h * 128 * K + (size_t)kt * 64;
        async_copy16(p,                  buf + h * 8192 + wave * 512);
        async_copy16(p + (size_t)64 * K, buf + h * 8192 + 4096 + wave * 512);
    };
    auto stB = [&](int h, int kt, uint16_t* buf) {
        const uint16_t* p = pB + (size_t)h * 128 * K + (size_t)kt * 64;
        async_copy16(p,                  buf + h * 8192 + wave * 512);
        async_copy16(p + (size_t)64 * K, buf + h * 8192 + 4096 + wave * 512);
    };

    // fragment addressing
    const int fm  = lane & 15;
    const int fr  = fm & 7;
    const int kgb = lane >> 4;                 // 0..3
    const int aoff = (wm2 * 64 + fm) * 64;
    const int boff = (wn2 * 32 + fm) * 64;

    // carried fragment registers
    short8 af[4][2];     // A frags for current QM half (32 VGPR)
    short8 b0[2][2];     // B frags QN=0 (16 VGPR), lives P1->P4
    short8 b1[2][2];     // B frags QN=1 (16 VGPR), lives P2->P3

    // ---- prologue: tile0 complete; {A0,B0,B1}(tile1) in flight ----
    stA(0, 0, sA0);
    stB(0, 0, sB0);
    stA(1, 0, sA0);
    stB(1, 0, sB0);
    stA(0, 1, sA1);
    stB(0, 1, sB1);
    stB(1, 1, sB1);
    asm volatile("s_waitcnt vmcnt(6)" ::: "memory");   // tile0 landed; 3 half-tiles in flight
    __builtin_amdgcn_s_barrier();
    SCHED0;

    const int niter2 = K / 128;    // 2 K-tiles per iteration
    for (int it = 0; it < niter2 - 1; ++it) {
        const int T = 2 * it;
        ITER_BODY(T, false);
    }
    {   // peeled final iteration (no stages beyond last tile)
        const int T = 2 * (niter2 - 1);
        ITER_BODY(T, true);
    }

    // ---- epilogue: C/D layout col = lane&15, row = (lane>>4)*4 + reg ----
    const int cr = (lane >> 4) * 4;
    const int cc = lane & 15;
#pragma unroll
    for (int qm = 0; qm < 2; qm++)
#pragma unroll
    for (int mi = 0; mi < 4; mi++) {
        const int gm = m0 + qm * 128 + wm2 * 64 + mi * 16 + cr;
#pragma unroll
        for (int qn = 0; qn < 2; qn++)
#pragma unroll
        for (int nj = 0; nj < 2; nj++) {
            const int gn = n0 + qn * 128 + wn2 * 32 + nj * 16 + cc;
            if (gn < nstore) {
                const float bv = bias[gn];
#pragma unroll
                for (int r = 0; r < 4; r++) {
                    float v = acc[qm][qn][mi][nj][r] + bv;
                    if (RELU) v = fmaxf(v, 0.f);
                    const size_t idx = (size_t)(gm + r) * ldc + gn;
                    if (OUTF32) ((float*)out)[idx] = v;
                    else        ((uint16_t*)out)[idx] = f2bf_bits(v);
                }
            }
        }
    }
}

// ---------- launch ----------

extern "C" void kernel_launch(void* const* d_in, const int* in_sizes, int n_in,
                              void* d_out, int out_size, void* d_ws, size_t ws_size,
                              hipStream_t stream) {
    (void)in_sizes; (void)n_in; (void)out_size; (void)ws_size;
    const float* X  = (const float*)d_in[1];
    const float* W0 = (const float*)d_in[3];
    const float* b0 = (const float*)d_in[4];
    const float* W1 = (const float*)d_in[5];
    const float* b1 = (const float*)d_in[6];
    const float* W2 = (const float*)d_in[7];
    const float* b2 = (const float*)d_in[8];

    const int M = 16384;     // 16 batches * 1024 pairs

    static bool attr_done = false;
    if (!attr_done) {
        (void)hipFuncSetAttribute((const void*)gemm256<true, false>,
                                  hipFuncAttributeMaxDynamicSharedMemorySize, 131072);
        attr_done = true;
    }

    char* w = (char*)d_ws;
    uint16_t* X0  = (uint16_t*)w; w += (size_t)M * 1024 * 2;
    uint16_t* X1  = (uint16_t*)w; w += (size_t)M * 2048 * 2;
    uint16_t* X2  = (uint16_t*)w; w += (size_t)M * 2048 * 2;
    uint16_t* W0b = (uint16_t*)w; w += (size_t)2048 * 1024 * 2;
    uint16_t* W1b = (uint16_t*)w; w += (size_t)2048 * 2048 * 2;
    uint16_t* W2b = (uint16_t*)w; w += (size_t)64 * 2048 * 2;

    cvt8<<<M * 1024 / 8 / 256, 256, 0, stream>>>(X, X0, M * 1024);
    cvt8<<<2048 * 1024 / 8 / 256, 256, 0, stream>>>(W0, W0b, 2048 * 1024);
    cvt8<<<2048 * 2048 / 8 / 256, 256, 0, stream>>>(W1, W1b, 2048 * 2048);
    cvt_pad_w2<<<64 * 2048 / 8 / 256, 256, 0, stream>>>(W2, W2b);

    // layer 0: [16384,1024] x [2048,1024]^T -> relu -> bf16; 256x256 8-phase
    gemm256<true, false><<<dim3((M / 256) * (2048 / 256)), 512, 131072, stream>>>(
        X0, W0b, b0, X1, 1024, 2048, 2048, 2048);
    // layer 1: [16384,2048] x [2048,2048]^T -> relu -> bf16; 256x256 8-phase
    gemm256<true, false><<<dim3((M / 256) * (2048 / 256)), 512, 131072, stream>>>(
        X1, W1b, b1, X2, 2048, 2048, 2048, 2048);
    // layer 2: [16384,2048] x [64(pad 51),2048]^T -> fp32; 32x64 tiles, 512 blocks
    gemm_bt<1, 2, false, true><<<dim3(M / 32), 256, 0, stream>>>(
        X2, W2b, b2, d_out, M, 64, 2048, 51, 51);
}

// Round 3
// 347.665 us; speedup vs baseline: 1.0633x; 1.0040x over previous
//
#include <hip/hip_runtime.h>
#include <hip/hip_bf16.h>
#include <stdint.h>

typedef __attribute__((ext_vector_type(8))) short short8;
typedef __attribute__((ext_vector_type(8))) uint16_t ushort8;
typedef __attribute__((ext_vector_type(4))) float floatx4;

#define TK 64   // K elems staged per barrier pair (legacy kernel)

// ---------- helpers ----------

__device__ __forceinline__ uint16_t f2bf_bits(float f) {
    uint32_t u = __builtin_bit_cast(uint32_t, f);
    u += 0x7FFFu + ((u >> 16) & 1u);
    return (uint16_t)(u >> 16);
}

__device__ __forceinline__ void async_copy16(const void* g, void* l) {
    // global -> LDS direct copy, 16B/lane; LDS dest = wave-uniform base + lane*16
    auto gp = (const __attribute__((address_space(1))) uint32_t*)(uintptr_t)g;
    auto lp = (__attribute__((address_space(3))) uint32_t*)(uint32_t)(uintptr_t)l;
    __builtin_amdgcn_global_load_lds(gp, lp, 16, 0, 0);
}

// ---------- fp32 -> bf16 conversion kernels ----------

__global__ void cvt8(const float* __restrict__ src, uint16_t* __restrict__ dst, int n) {
    int i = (blockIdx.x * 256 + threadIdx.x) * 8;
    if (i >= n) return;
    floatx4 a = *(const floatx4*)(src + i);
    floatx4 b = *(const floatx4*)(src + i + 4);
    ushort8 o;
#pragma unroll
    for (int k = 0; k < 4; k++) {
        o[k]     = f2bf_bits(a[k]);
        o[k + 4] = f2bf_bits(b[k]);
    }
    *(ushort8*)(dst + i) = o;
}

// W2 [51][2048] fp32 -> [64][2048] bf16, rows >= 51 zeroed
__global__ void cvt_pad_w2(const float* __restrict__ src, uint16_t* __restrict__ dst) {
    int i = (blockIdx.x * 256 + threadIdx.x) * 8;   // over 64*2048
    int row = i >> 11;
    ushort8 o;
    if (row < 51) {
        floatx4 a = *(const floatx4*)(src + i);
        floatx4 b = *(const floatx4*)(src + i + 4);
#pragma unroll
        for (int k = 0; k < 4; k++) {
            o[k]     = f2bf_bits(a[k]);
            o[k + 4] = f2bf_bits(b[k]);
        }
    } else {
#pragma unroll
        for (int k = 0; k < 8; k++) o[k] = 0;
    }
    *(ushort8*)(dst + i) = o;
}

// ---------- legacy small-tile GEMM (kept for layer 2: N=64) ----------
// C[m,n] = act( sum_k A[m,k]*W[n,k] + bias[n] )

template <int MI, int NJ, bool RELU, bool OUTF32>
__global__ __launch_bounds__(256, 2)
void gemm_bt(const uint16_t* __restrict__ A,
             const uint16_t* __restrict__ W,
             const float* __restrict__ bias,
             void* __restrict__ out,
             int M, int N, int K, int ldc, int nstore)
{
    constexpr int TMv = MI * 32;
    constexpr int TNv = NJ * 32;
    constexpr int ACH = TMv / 32;
    constexpr int BCH = TNv / 32;

    __shared__ alignas(16) uint16_t sA[TMv * TK];
    __shared__ alignas(16) uint16_t sB[TNv * TK];

    const int tid  = threadIdx.x;
    const int wave = tid >> 6;
    const int lane = tid & 63;

    const int f   = blockIdx.x;
    const int xcd = f & 7;
    const int loc = f >> 3;
    const int per = (int)gridDim.x >> 3;
    const int nt  = N / TNv;
    const int n_t = loc % nt;
    const int m_t = xcd * (per / nt) + loc / nt;
    const int n0 = n_t * TNv;
    const int m0 = m_t * TMv;

    floatx4 acc[MI][NJ];
    const floatx4 zero = {0.f, 0.f, 0.f, 0.f};
#pragma unroll
    for (int i = 0; i < MI; i++)
#pragma unroll
        for (int j = 0; j < NJ; j++) acc[i][j] = zero;

    const int wr = (wave >> 1) * MI * 16;
    const int wc = (wave & 1) * NJ * 16;

    const int sr   = lane >> 3;
    const int scol = ((lane & 7) ^ sr) * 8;

    const uint16_t* ap[ACH];
    const uint16_t* bp[BCH];
#pragma unroll
    for (int t = 0; t < ACH; t++)
        ap[t] = A + (size_t)(m0 + (wave + 4 * t) * 8 + sr) * K + scol;
#pragma unroll
    for (int t = 0; t < BCH; t++)
        bp[t] = W + (size_t)(n0 + (wave + 4 * t) * 8 + sr) * K + scol;

    const int fm = lane & 15;
    const int fr = fm & 7;
    const int kgb = lane >> 4;

    const int niter = K / TK;
    for (int it = 0; it < niter; it++) {
#pragma unroll
        for (int t = 0; t < ACH; t++) {
            async_copy16(ap[t], sA + (wave + 4 * t) * 512);
            ap[t] += TK;
        }
#pragma unroll
        for (int t = 0; t < BCH; t++) {
            async_copy16(bp[t], sB + (wave + 4 * t) * 512);
            bp[t] += TK;
        }
        __syncthreads();

#pragma unroll
        for (int kk = 0; kk < 2; kk++) {
            const int slot = ((kgb + 4 * kk) ^ fr) * 8;
            short8 af[MI], bfr[NJ];
#pragma unroll
            for (int i = 0; i < MI; i++)
                af[i] = *(const short8*)(sA + (wr + i * 16 + fm) * TK + slot);
#pragma unroll
            for (int j = 0; j < NJ; j++)
                bfr[j] = *(const short8*)(sB + (wc + j * 16 + fm) * TK + slot);
#pragma unroll
            for (int i = 0; i < MI; i++)
#pragma unroll
                for (int j = 0; j < NJ; j++)
                    acc[i][j] = __builtin_amdgcn_mfma_f32_16x16x32_bf16(af[i], bfr[j], acc[i][j], 0, 0, 0);
        }
        __syncthreads();
    }

    const int cr = (lane >> 4) * 4;
    const int cc = lane & 15;
#pragma unroll
    for (int i = 0; i < MI; i++) {
        const int gmb = m0 + wr + i * 16 + cr;
#pragma unroll
        for (int j = 0; j < NJ; j++) {
            const int gn = n0 + wc + j * 16 + cc;
            if (gn < nstore) {
                const float bv = bias[gn];
#pragma unroll
                for (int r = 0; r < 4; r++) {
                    float v = acc[i][j][r] + bv;
                    if (RELU) v = fmaxf(v, 0.f);
                    const size_t idx = (size_t)(gmb + r) * ldc + gn;
                    if (OUTF32) ((float*)out)[idx] = v;
                    else        ((uint16_t*)out)[idx] = f2bf_bits(v);
                }
            }
        }
    }
}

// ---------- 256x256 8-phase GEMM, SINGLE barrier per phase ----------
// 8 waves (2M x 4N), 512 threads, BK=64, LDS 128 KiB (2 bufs x (A 256x64 + B 256x64)).
// Phase = { ds_reads(p) + stage(p) issue; lgkmcnt(0); [vmcnt ckpt P4/P8]; s_barrier;
//           setprio(1) 16 MFMA setprio(0) }.
// Invariant at every barrier: all this wave's ds_reads complete (lgkm0 pre-barrier),
// so any stage issued in a LATER phase into the same region is safe; vmcnt ckpt
// pre-barrier makes the next tile block-wide visible after the barrier.
// Reads/stages of phase p+1 issue while phase-p MFMAs drain (pipe overlap).
// Quadrant walk Q00->Q01->Q11->Q10 with fragment register-carry:
//   P1: A0+B0 [12 rd]  P2: B1 [4 rd]  P3: A1 [8 rd]  P4: none [0 rd]  (min 24/K-tile)

#define SCHED0 __builtin_amdgcn_sched_barrier(0)

#define LOAD_A(SA, QM) do { \
    const uint16_t* _p = (SA) + (QM) * 8192 + aoff; \
    _Pragma("unroll") \
    for (int kk = 0; kk < 2; kk++) { \
      const int sl = ((kgb + 4 * kk) ^ fr) * 8; \
      _Pragma("unroll") \
      for (int mi = 0; mi < 4; mi++) \
        af[mi][kk] = *(const short8*)(_p + mi * 1024 + sl); \
    } } while (0)

#define LOAD_B(SB, QN, BF) do { \
    const uint16_t* _p = (SB) + (QN) * 8192 + boff; \
    _Pragma("unroll") \
    for (int kk = 0; kk < 2; kk++) { \
      const int sl = ((kgb + 4 * kk) ^ fr) * 8; \
      _Pragma("unroll") \
      for (int nj = 0; nj < 2; nj++) \
        BF[nj][kk] = *(const short8*)(_p + nj * 1024 + sl); \
    } } while (0)

// sync: reads pinned above lgkm0; one barrier; MFMA pinned after
#define PH_SYNC \
    SCHED0; \
    asm volatile("s_waitcnt lgkmcnt(0)" ::: "memory"); \
    SCHED0; \
    __builtin_amdgcn_s_barrier(); \
    SCHED0;

#define PH_SYNC_CKPT(NSTR) \
    SCHED0; \
    asm volatile("s_waitcnt lgkmcnt(0)" ::: "memory"); \
    SCHED0; \
    asm volatile("s_waitcnt vmcnt(" NSTR ")" ::: "memory"); \
    SCHED0; \
    __builtin_amdgcn_s_barrier(); \
    SCHED0;

#define MFMA_CL(QM, QN, BF) \
    __builtin_amdgcn_s_setprio(1); \
    _Pragma("unroll") \
    for (int kk = 0; kk < 2; kk++) \
      _Pragma("unroll") \
      for (int mi = 0; mi < 4; mi++) \
        _Pragma("unroll") \
        for (int nj = 0; nj < 2; nj++) \
          acc[QM][QN][mi][nj] = __builtin_amdgcn_mfma_f32_16x16x32_bf16( \
              af[mi][kk], BF[nj][kk], acc[QM][QN][mi][nj], 0, 0, 0); \
    __builtin_amdgcn_s_setprio(0); \
    SCHED0;

// One iteration = 2 K-tiles (T in buf0, T+1 in buf1), 8 phases, 8 barriers.
#define ITER_BODY(T, LAST) \
    /* P1: Q00(T); stage A1(T+1)->buf1 (buf1-A1 last read prev P7) */ \
    LOAD_A(sA0, 0); \
    LOAD_B(sB0, 0, b0); \
    stA(1, (T) + 1, sA1); \
    PH_SYNC; \
    MFMA_CL(0, 0, b0); \
    /* P2: Q01(T); stage A0(T+2)->buf0 (A0 reads done P1) */ \
    LOAD_B(sB0, 1, b1); \
    if (!(LAST)) stA(0, (T) + 2, sA0); \
    PH_SYNC; \
    MFMA_CL(0, 1, b1); \
    /* P3: Q11(T); stage B0(T+2)->buf0 (B0 reads done P1) */ \
    LOAD_A(sA0, 1); \
    if (!(LAST)) stB(0, (T) + 2, sB0); \
    PH_SYNC; \
    MFMA_CL(1, 1, b1); \
    /* P4: Q10(T) no reads; stage B1(T+2)->buf0 (B1 reads done P2); ckpt tile T+1 */ \
    if (!(LAST)) { \
      stB(1, (T) + 2, sB0); \
      PH_SYNC_CKPT("6"); \
    } else { \
      PH_SYNC_CKPT("0"); \
    } \
    MFMA_CL(1, 0, b0); \
    /* P5: Q00(T+1); stage A1(T+2)->buf0 (A1 reads done P3) */ \
    LOAD_A(sA1, 0); \
    LOAD_B(sB1, 0, b0); \
    if (!(LAST)) stA(1, (T) + 2, sA0); \
    PH_SYNC; \
    MFMA_CL(0, 0, b0); \
    /* P6: Q01(T+1); stage A0(T+3)->buf1 */ \
    LOAD_B(sB1, 1, b1); \
    if (!(LAST)) stA(0, (T) + 3, sA1); \
    PH_SYNC; \
    MFMA_CL(0, 1, b1); \
    /* P7: Q11(T+1); stage B0(T+3)->buf1 */ \
    LOAD_A(sA1, 1); \
    if (!(LAST)) stB(0, (T) + 3, sB1); \
    PH_SYNC; \
    MFMA_CL(1, 1, b1); \
    /* P8: Q10(T+1) no reads; stage B1(T+3)->buf1; ckpt tile T+2 */ \
    if (!(LAST)) { \
      stB(1, (T) + 3, sB1); \
      PH_SYNC_CKPT("6"); \
    } else { \
      PH_SYNC; \
    } \
    MFMA_CL(1, 0, b0);

template <bool RELU, bool OUTF32>
__global__ __launch_bounds__(512, 2)
void gemm256(const uint16_t* __restrict__ A,
             const uint16_t* __restrict__ W,
             const float* __restrict__ bias,
             void* __restrict__ out,
             int K, int N, int ldc, int nstore)
{
    extern __shared__ uint16_t smem[];   // 65536 uint16 = 128 KiB
    uint16_t* sA0 = smem;                // A buf0 (even K-tiles)
    uint16_t* sA1 = smem + 16384;        // A buf1 (odd K-tiles)
    uint16_t* sB0 = smem + 32768;
    uint16_t* sB1 = smem + 49152;

    const int tid  = threadIdx.x;
    const int wave = tid >> 6;          // 0..7
    const int lane = tid & 63;
    const int wm2  = wave >> 2;         // 0..1
    const int wn2  = wave & 3;          // 0..3

    // XCD-aware tile assignment (grid % 8 == 0, per % ntn == 0)
    const int f   = blockIdx.x;
    const int xcd = f & 7;
    const int loc = f >> 3;
    const int per = (int)gridDim.x >> 3;
    const int ntn = N / 256;
    const int n_t = loc % ntn;
    const int m_t = xcd * (per / ntn) + loc / ntn;
    const int m0 = m_t * 256;
    const int n0 = n_t * 256;

    floatx4 acc[2][2][4][2];
    const floatx4 zero = {0.f, 0.f, 0.f, 0.f};
#pragma unroll
    for (int qm = 0; qm < 2; qm++)
#pragma unroll
    for (int qn = 0; qn < 2; qn++)
#pragma unroll
    for (int mi = 0; mi < 4; mi++)
#pragma unroll
    for (int nj = 0; nj < 2; nj++) acc[qm][qn][mi][nj] = zero;

    // staging addressing: 1KB chunk = 8 rows x 64 cols; slot s of row r holds
    // global k-group s ^ (r&7)  (bank-conflict-free frag reads; measured 0-conflict)
    const int srow = lane >> 3;
    const int scol = ((lane & 7) ^ srow) * 8;
    const uint16_t* pA = A + (size_t)(m0 + wave * 8 + srow) * K + scol;
    const uint16_t* pB = W + (size_t)(n0 + wave * 8 + srow) * K + scol;

    auto stA = [&](int h, int kt, uint16_t* buf) {
        const uint16_t* p = pA + (size_t)h * 128 * K + (size_t)kt * 64;
        async_copy16(p,                  buf + h * 8192 + wave * 512);
        async_copy16(p + (size_t)64 * K, buf + h * 8192 + 4096 + wave * 512);
    };
    auto stB = [&](int h, int kt, uint16_t* buf) {
        const uint16_t* p = pB + (size_t)h * 128 * K + (size_t)kt * 64;
        async_copy16(p,                  buf + h * 8192 + wave * 512);
        async_copy16(p + (size_t)64 * K, buf + h * 8192 + 4096 + wave * 512);
    };

    // fragment addressing
    const int fm  = lane & 15;
    const int fr  = fm & 7;
    const int kgb = lane >> 4;                 // 0..3
    const int aoff = (wm2 * 64 + fm) * 64;
    const int boff = (wn2 * 32 + fm) * 64;

    // carried fragment registers
    short8 af[4][2];     // A frags for current QM half (32 VGPR)
    short8 b0[2][2];     // B frags QN=0 (16 VGPR), lives P1->P4
    short8 b1[2][2];     // B frags QN=1 (16 VGPR), lives P2->P3

    // ---- prologue: tile0 complete; {A0,B0,B1}(tile1) in flight ----
    stA(0, 0, sA0);
    stB(0, 0, sB0);
    stA(1, 0, sA0);
    stB(1, 0, sB0);
    stA(0, 1, sA1);
    stB(0, 1, sB1);
    stB(1, 1, sB1);
    asm volatile("s_waitcnt vmcnt(6)" ::: "memory");   // tile0 landed; 3 half-tiles in flight
    __builtin_amdgcn_s_barrier();
    SCHED0;

    const int niter2 = K / 128;    // 2 K-tiles per iteration
    for (int it = 0; it < niter2 - 1; ++it) {
        const int T = 2 * it;
        ITER_BODY(T, false);
    }
    {   // peeled final iteration (no stages beyond last tile)
        const int T = 2 * (niter2 - 1);
        ITER_BODY(T, true);
    }

    // ---- epilogue: C/D layout col = lane&15, row = (lane>>4)*4 + reg ----
    const int cr = (lane >> 4) * 4;
    const int cc = lane & 15;
#pragma unroll
    for (int qm = 0; qm < 2; qm++)
#pragma unroll
    for (int mi = 0; mi < 4; mi++) {
        const int gm = m0 + qm * 128 + wm2 * 64 + mi * 16 + cr;
#pragma unroll
        for (int qn = 0; qn < 2; qn++)
#pragma unroll
        for (int nj = 0; nj < 2; nj++) {
            const int gn = n0 + qn * 128 + wn2 * 32 + nj * 16 + cc;
            if (gn < nstore) {
                const float bv = bias[gn];
#pragma unroll
                for (int r = 0; r < 4; r++) {
                    float v = acc[qm][qn][mi][nj][r] + bv;
                    if (RELU) v = fmaxf(v, 0.f);
                    const size_t idx = (size_t)(gm + r) * ldc + gn;
                    if (OUTF32) ((float*)out)[idx] = v;
                    else        ((uint16_t*)out)[idx] = f2bf_bits(v);
                }
            }
        }
    }
}

// ---------- launch ----------

extern "C" void kernel_launch(void* const* d_in, const int* in_sizes, int n_in,
                              void* d_out, int out_size, void* d_ws, size_t ws_size,
                              hipStream_t stream) {
    (void)in_sizes; (void)n_in; (void)out_size; (void)ws_size;
    const float* X  = (const float*)d_in[1];
    const float* W0 = (const float*)d_in[3];
    const float* b0 = (const float*)d_in[4];
    const float* W1 = (const float*)d_in[5];
    const float* b1 = (const float*)d_in[6];
    const float* W2 = (const float*)d_in[7];
    const float* b2 = (const float*)d_in[8];

    const int M = 16384;     // 16 batches * 1024 pairs

    static bool attr_done = false;
    if (!attr_done) {
        (void)hipFuncSetAttribute((const void*)gemm256<true, false>,
                                  hipFuncAttributeMaxDynamicSharedMemorySize, 131072);
        attr_done = true;
    }

    char* w = (char*)d_ws;
    uint16_t* X0  = (uint16_t*)w; w += (size_t)M * 1024 * 2;
    uint16_t* X1  = (uint16_t*)w; w += (size_t)M * 2048 * 2;
    uint16_t* X2  = (uint16_t*)w; w += (size_t)M * 2048 * 2;
    uint16_t* W0b = (uint16_t*)w; w += (size_t)2048 * 1024 * 2;
    uint16_t* W1b = (uint16_t*)w; w += (size_t)2048 * 2048 * 2;
    uint16_t* W2b = (uint16_t*)w; w += (size_t)64 * 2048 * 2;

    cvt8<<<M * 1024 / 8 / 256, 256, 0, stream>>>(X, X0, M * 1024);
    cvt8<<<2048 * 1024 / 8 / 256, 256, 0, stream>>>(W0, W0b, 2048 * 1024);
    cvt8<<<2048 * 2048 / 8 / 256, 256, 0, stream>>>(W1, W1b, 2048 * 2048);
    cvt_pad_w2<<<64 * 2048 / 8 / 256, 256, 0, stream>>>(W2, W2b);

    // layer 0: [16384,1024] x [2048,1024]^T -> relu -> bf16; 256x256 8-phase
    gemm256<true, false><<<dim3((M / 256) * (2048 / 256)), 512, 131072, stream>>>(
        X0, W0b, b0, X1, 1024, 2048, 2048, 2048);
    // layer 1: [16384,2048] x [2048,2048]^T -> relu -> bf16; 256x256 8-phase
    gemm256<true, false><<<dim3((M / 256) * (2048 / 256)), 512, 131072, stream>>>(
        X1, W1b, b1, X2, 2048, 2048, 2048, 2048);
    // layer 2: [16384,2048] x [64(pad 51),2048]^T -> fp32; 32x64 tiles, 512 blocks
    gemm_bt<1, 2, false, true><<<dim3(M / 32), 256, 0, stream>>>(
        X2, W2b, b2, d_out, M, 64, 2048, 51, 51);
}